// Round 1
// baseline (17108.705 us; speedup 1.0000x reference)
//
#include <hip/hip_runtime.h>
#include <cfloat>
#include <math.h>

#define N 512

// One block, 512 threads: thread t owns column (t+1) in the 1-indexed JV
// formulation. Mirrors the numpy reference exactly (float64 math, contract
// off, argmin tie-break = smallest column index).
__global__ __launch_bounds__(512, 1) void tofu_solver(
    const float* __restrict__ dgm,   // [N,2] row-major
    const float* __restrict__ dgm_x, // [N,2]
    float* __restrict__ out)         // [1]
{
#pragma clang fp contract(off)
    __shared__ double b_lds[N];      // dgm births (double)
    __shared__ double d_lds[N];      // dgm deaths
    __shared__ double u_lds[N + 1];  // row duals, 1-indexed
    __shared__ int    p_lds[N + 1];  // p[j] = row matched to column j
    __shared__ int    way_lds[N + 1];
    __shared__ double wredv[8];
    __shared__ int    wredi[8];
    __shared__ double bc_delta;
    __shared__ int    bc_j1;

    const int tid = threadIdx.x;      // 0..511
    const int col = tid + 1;          // 1..512
    const int lane = tid & 63;
    const int wid  = tid >> 6;

    // Stage dgm rows into LDS (broadcast-read in hot loop); keep this
    // thread's dgm_x point in registers.
    b_lds[tid] = (double)dgm[2 * tid];
    d_lds[tid] = (double)dgm[2 * tid + 1];
    const double xb = (double)dgm_x[2 * tid];
    const double xd = (double)dgm_x[2 * tid + 1];

    for (int k = tid; k <= N; k += N) { u_lds[k] = 0.0; p_lds[k] = 0; way_lds[k] = 0; }
    double v_j = 0.0;                 // column dual (register)
    __syncthreads();

    for (int i = 1; i <= N; ++i) {
        double minv_j = DBL_MAX;
        bool used_j = false;
        if (tid == 0) p_lds[0] = i;
        int j0 = 0;
        __syncthreads();              // p writes (prev augment) + p[0]=i visible

        while (true) {
            if (col == j0) used_j = true;       // mark column j0 used
            const int i0 = p_lds[j0];           // uniform read
            const double u_i0 = u_lds[i0];
            if (!used_j) {
                const double db = b_lds[i0 - 1] - xb;
                const double dd = d_lds[i0 - 1] - xd;
                const double c  = sqrt(db * db + dd * dd);   // contract off: matches np
                const double cur = (c - u_i0) - v_j;         // (cost - u) - v, np order
                if (cur < minv_j) { minv_j = cur; way_lds[col] = j0; }
            }

            // argmin over free columns: (value, smallest index)
            double rv = used_j ? DBL_MAX : minv_j;
            int ri = col;
            #pragma unroll
            for (int off = 32; off >= 1; off >>= 1) {
                double ov = __shfl_down(rv, off, 64);
                int    oi = __shfl_down(ri, off, 64);
                if (ov < rv || (ov == rv && oi < ri)) { rv = ov; ri = oi; }
            }
            if (lane == 0) { wredv[wid] = rv; wredi[wid] = ri; }
            __syncthreads();
            if (tid == 0) {
                double bv = wredv[0]; int bi = wredi[0];
                #pragma unroll
                for (int w = 1; w < 8; ++w) {
                    double ov = wredv[w]; int oi = wredi[w];
                    if (ov < bv || (ov == bv && oi < bi)) { bv = ov; bi = oi; }
                }
                bc_delta = bv; bc_j1 = bi;
            }
            __syncthreads();
            const double delta = bc_delta;
            const int j1 = bc_j1;

            // dual updates: path rows are distinct -> plain LDS RMW is race-free
            if (used_j) {
                v_j -= delta;
                u_lds[p_lds[col]] += delta;
            } else {
                minv_j -= delta;
            }
            if (tid == 0) u_lds[i] += delta;    // column 0: p[0] = i, always used

            j0 = j1;
            __syncthreads();                    // u/way updates visible for next iter
            if (p_lds[j0] == 0) break;          // uniform decision
        }

        __syncthreads();                        // everyone past the p[j0] read
        if (tid == 0) {                         // augment along way[] (serial, short)
            int j = j0;
            while (j) { int jn = way_lds[j]; p_lds[j] = p_lds[jn]; j = jn; }
        }
        // next row's start barrier orders these p writes before any p read
    }

    __syncthreads();
    // loss = 0.5 * sum_j ||dgm[p[j]-1] - dgm_x[j-1]||^2  (diffs in f32 like ref)
    const int r = p_lds[col] - 1;
    const float fb = dgm[2 * r]     - dgm_x[2 * tid];
    const float fd = dgm[2 * r + 1] - dgm_x[2 * tid + 1];
    double contrib = (double)fb * (double)fb + (double)fd * (double)fd;
    #pragma unroll
    for (int off = 32; off >= 1; off >>= 1)
        contrib += __shfl_down(contrib, off, 64);
    if (lane == 0) wredv[wid] = contrib;
    __syncthreads();
    if (tid == 0) {
        double s = 0.0;
        #pragma unroll
        for (int w = 0; w < 8; ++w) s += wredv[w];
        out[0] = (float)(0.5 * s);
    }
}

extern "C" void kernel_launch(void* const* d_in, const int* in_sizes, int n_in,
                              void* d_out, int out_size, void* d_ws, size_t ws_size,
                              hipStream_t stream) {
    const float* dgm   = (const float*)d_in[0];
    const float* dgm_x = (const float*)d_in[1];
    float* out = (float*)d_out;
    tofu_solver<<<1, 512, 0, stream>>>(dgm, dgm_x, out);
}

// Round 2
// 9903.261 us; speedup vs baseline: 1.7276x; 1.7276x over previous
//
#include <hip/hip_runtime.h>
#include <cfloat>
#include <math.h>

#define N 512

// Monotone map: IEEE-754 double -> u64 with value ordering == unsigned ordering.
__device__ __forceinline__ unsigned long long map_f64(double x) {
    unsigned long long b = (unsigned long long)__double_as_longlong(x);
    return b ^ ((b >> 63) ? 0xFFFFFFFFFFFFFFFFull : 0x8000000000000000ull);
}
__device__ __forceinline__ double unmap_f64(unsigned long long b) {
    b ^= ((b >> 63) ? 0x8000000000000000ull : 0xFFFFFFFFFFFFFFFFull);
    return __longlong_as_double((long long)b);
}

// One block, 512 threads; thread t owns column t+1 (1-indexed JV).
// Exact Jonker-Volgenant with LAPJV warm start (column reduction + greedy
// tight matching), f64 duals. Key truncation (low 9 mantissa bits -> col
// index) perturbs costs by <=2^-42 rel — assignment unchanged a.s.
__global__ __launch_bounds__(512, 1) void tofu_solver(
    const float* __restrict__ dgm,   // [N,2]
    const float* __restrict__ dgm_x, // [N,2]
    float* __restrict__ out)         // [1]
{
#pragma clang fp contract(off)
    __shared__ double b_lds[N];
    __shared__ double d_lds[N];
    __shared__ double u_lds[N + 1];
    __shared__ int    p_lds[N + 1];
    __shared__ int    way_lds[N + 1];   // also reused as row-taken flags in init
    __shared__ int    argmin_lds[N + 1];
    __shared__ int    freelist[N];
    __shared__ int    nfree_s;
    __shared__ unsigned long long part[2][8];  // parity-double-buffered wave partials
    __shared__ double red8[8];

    const int tid  = threadIdx.x;     // 0..511
    const int col  = tid + 1;         // 1..512
    const int lane = tid & 63;
    const int wid  = tid >> 6;

    // ---- init ----
    b_lds[tid] = (double)dgm[2 * tid];
    d_lds[tid] = (double)dgm[2 * tid + 1];
    const double xb = (double)dgm_x[2 * tid];
    const double xd = (double)dgm_x[2 * tid + 1];
    u_lds[col] = 0.0; p_lds[col] = 0; way_lds[col] = 0;
    if (tid == 0) { u_lds[0] = 0.0; p_lds[0] = 0; way_lds[0] = 0; }
    __syncthreads();

    // ---- column reduction: v[j] = min_i c[i,j]  (v stays in a register) ----
    double v_j = DBL_MAX; int imin = 0;
    for (int i = 0; i < N; ++i) {                 // broadcast LDS reads
        const double db = b_lds[i] - xb;
        const double dd = d_lds[i] - xd;
        const double c  = sqrt(db * db + dd * dd);
        if (c < v_j) { v_j = c; imin = i; }
    }
    argmin_lds[col] = imin + 1;
    __syncthreads();

    // ---- greedy tight matching on column argmins (thread 0, ~µs) ----
    if (tid == 0) {
        for (int j = 1; j <= N; ++j) {
            const int r = argmin_lds[j];
            if (!way_lds[r]) { way_lds[r] = 1; p_lds[j] = r; }  // edge tight: c=v[j], u=0
        }
        int nf = 0;
        for (int r = 1; r <= N; ++r) if (!way_lds[r]) freelist[nf++] = r;
        nfree_s = nf;
    }
    __syncthreads();
    const int nfree = nfree_s;

    // ---- Dijkstra augmentation for each free row ----
    for (int kk = 0; kk < nfree; ++kk) {
        __syncthreads();                          // prev row's p/u writes visible
        const int i = freelist[kk];               // uniform broadcast
        const int p_own = p_lds[col];             // my column's matched row (0 if free)
        if (tid == 0) p_lds[0] = i;               // chain terminator for augment

        double minv = DBL_MAX;
        bool   used = false;
        double du = 0.0, du0 = 0.0;
        int j0 = 0, i0 = i, par = 0;

        while (true) {
            if (col == j0) used = true;
            const double u_i0 = u_lds[i0];        // untouched this Dijkstra (see note)
            if (!used) {
                const double db = b_lds[i0 - 1] - xb;
                const double dd = d_lds[i0 - 1] - xd;
                const double c  = sqrt(db * db + dd * dd);
                const double cur = (c - u_i0) - v_j;
                if (cur < minv) { minv = cur; way_lds[col] = j0; }
            }
            // packed key: value-ordered u64, low 9 bits = col-1 (index tie-break)
            unsigned long long key = used ? 0xFFFFFFFFFFFFFFFFull
                : ((map_f64(minv) & ~511ull) | (unsigned long long)(col - 1));
            #pragma unroll
            for (int off = 32; off >= 1; off >>= 1) {
                const unsigned long long o = __shfl_down(key, off, 64);
                if (o < key) key = o;
            }
            if (lane == 0) part[par][wid] = key;
            __syncthreads();                      // the ONE barrier per iteration
            unsigned long long km = part[par][0];
            #pragma unroll
            for (int w = 1; w < 8; ++w) {
                const unsigned long long o = part[par][w];
                if (o < km) km = o;
            }
            const int j1 = (int)(km & 511ull) + 1;
            const double delta = unmap_f64(km & ~511ull);  // <= every free minv

            if (used) { v_j -= delta; du += delta; }
            else      { minv -= delta; }
            if (tid == 0) du0 += delta;           // row i (virtual column 0)

            j0 = j1;
            i0 = p_lds[j1];                       // next i0 AND break check (uniform)
            par ^= 1;
            if (i0 == 0) break;
        }

        __syncthreads();                          // all past p[j1]/u reads
        if (used) u_lds[p_own] += du;             // flush register-accumulated duals
        if (tid == 0) {
            u_lds[i] += du0;
            int j = j0;                           // augment along way[]
            while (j) { const int jn = way_lds[j]; p_lds[j] = p_lds[jn]; j = jn; }
        }
    }
    __syncthreads();

    // ---- loss = 0.5 * sum_j ||dgm[p[j]-1] - dgm_x[j-1]||^2 (f32 diffs like ref) ----
    const int r = p_lds[col] - 1;
    const float fb = dgm[2 * r]     - dgm_x[2 * tid];
    const float fd = dgm[2 * r + 1] - dgm_x[2 * tid + 1];
    double contrib = (double)fb * (double)fb + (double)fd * (double)fd;
    #pragma unroll
    for (int off = 32; off >= 1; off >>= 1)
        contrib += __shfl_down(contrib, off, 64);
    if (lane == 0) red8[wid] = contrib;
    __syncthreads();
    if (tid == 0) {
        double s = 0.0;
        #pragma unroll
        for (int w = 0; w < 8; ++w) s += red8[w];
        out[0] = (float)(0.5 * s);
    }
}

extern "C" void kernel_launch(void* const* d_in, const int* in_sizes, int n_in,
                              void* d_out, int out_size, void* d_ws, size_t ws_size,
                              hipStream_t stream) {
    const float* dgm   = (const float*)d_in[0];
    const float* dgm_x = (const float*)d_in[1];
    float* out = (float*)d_out;
    tofu_solver<<<1, 512, 0, stream>>>(dgm, dgm_x, out);
}